// Round 1
// 400.813 us; speedup vs baseline: 1.1063x; 1.1063x over previous
//
#include <hip/hip_runtime.h>
#include <hip/hip_fp16.h>

// Problem:  x (8,64,256,256) fp32; 4 window quadrants of 128x128
//   dynamic conv weights from tiny MHA over 36 tokens + SE gate
//   out = x + LN_c(conv_win(x))    ALL I/O fp32.
// Internals: conv runs on FP16 MFMA (not bf16!) — LN divides by the small
//   channel-wise sigma of a bias-dominated conv output, amplifying rounding
//   ~5-10x; bf16 measured 0.5625 absmax, fp16 is 8x tighter. Residual uses
//   fp32 x re-read from global (L2-warm). Accumulate/LN in fp32.
//
// R1 change: tw_kernel rewritten. Old version gathered 64 distinct weight
//   rows per wave-instruction (64 cache lines/instr) and read qkvb at LDS
//   stride 192 (mod 32 == 0 -> 32-way bank conflict). New version: j-major
//   lane mapping (weight rows broadcast across lanes), 4-wide register
//   blocking with float4 operand loads, LDS pitches 68/196 (mod 32 != 0,
//   rows 16B-aligned for b128). conv_kernel untouched.

typedef __attribute__((ext_vector_type(8))) _Float16 half8;
typedef __attribute__((ext_vector_type(4))) float floatx4;
typedef unsigned short ushort_t;

__device__ __forceinline__ ushort_t f2h(float f) {
  union { _Float16 h; ushort_t u; } cv;
  cv.h = (_Float16)f;   // RTE
  return cv.u;
}

// dynamic weights W2[win][tap][o][i] (fp16) — static device buffer
__device__ __align__(16) ushort_t g_W2[4 * 9 * 64 * 64];

// ---------------------------------------------------------------------------
// Kernel 1: 64 blocks, one per attention batch o -> g_W2[win][tap][o][i]
// LDS layout (floats):
//   k0 / mat : [36][68]   (pitch 68: mod32=4, 16B-aligned rows)
//   qkvb     : [36][196]  (pitch 196: q at +0, k at +64, v at +128)
//   aout     : [36][68]
// ---------------------------------------------------------------------------
__global__ __launch_bounds__(256) void tw_kernel(
    const float* __restrict__ conv_w,
    const float* __restrict__ w_qkv,
    const float* __restrict__ b_qkv,
    const float* __restrict__ w_out,
    const float* __restrict__ b_out,
    const float* __restrict__ se_w1,
    const float* __restrict__ se_b1,
    const float* __restrict__ se_w2,
    const float* __restrict__ se_b2)
{
  __shared__ __align__(16) float smem[11952];  // 47.8 KB
  const int t = threadIdx.x;
  const int o = blockIdx.x;
  float* k0   = smem;           // [36][68], later reused for mat
  float* qkvb = smem + 2448;    // [36][196]
  float* aout = smem + 9504;    // [36][68]

  // kern0[l][i] = conv_w[win][o][i][t9],  l = win*9 + t9
  for (int idx = t; idx < 36 * 64; idx += 256) {
    int l = idx >> 6, i = idx & 63;
    int win = l / 9, t9 = l - win * 9;
    k0[l * 68 + i] = conv_w[((win * 64 + o) * 64 + i) * 9 + t9];
  }
  __syncthreads();

  // qkv[l][j] = kern0[l][:] . w_qkv[j][:] + b_qkv[j]
  // j-major lane mapping: lanes in a wave share jg -> weight reads broadcast.
  // Each thread computes 4 consecutive j for one l (register blocking).
  for (int idx = t; idx < 48 * 36; idx += 256) {
    int jg = idx / 36, l = idx - jg * 36;
    int j = jg << 2;
    const float* kr = k0 + l * 68;
    const float* w0 = w_qkv + j * 64;
    float a0 = 0.f, a1 = 0.f, a2 = 0.f, a3 = 0.f;
    #pragma unroll
    for (int i = 0; i < 64; i += 4) {
      floatx4 kf  = *(const floatx4*)(kr + i);
      floatx4 wf0 = *(const floatx4*)(w0 + i);
      floatx4 wf1 = *(const floatx4*)(w0 + 64 + i);
      floatx4 wf2 = *(const floatx4*)(w0 + 128 + i);
      floatx4 wf3 = *(const floatx4*)(w0 + 192 + i);
      #pragma unroll
      for (int e = 0; e < 4; ++e) {
        a0 += kf[e] * wf0[e];
        a1 += kf[e] * wf1[e];
        a2 += kf[e] * wf2[e];
        a3 += kf[e] * wf3[e];
      }
    }
    floatx4 r = { a0 + b_qkv[j],     a1 + b_qkv[j + 1],
                  a2 + b_qkv[j + 2], a3 + b_qkv[j + 3] };
    *(floatx4*)(qkvb + l * 196 + j) = r;
  }
  __syncthreads();

  // attention per (h, l): softmax(q.k) @ v   (q scaled by 8^-0.5)
  // K/V reads: all lanes in a 36-lane group read the same row -> broadcast.
  for (int idx = t; idx < 288; idx += 256) {
    int h = idx / 36, l = idx - h * 36;
    const int hq = h << 3;
    floatx4 q0 = *(const floatx4*)(qkvb + l * 196 + hq);
    floatx4 q1 = *(const floatx4*)(qkvb + l * 196 + hq + 4);
    float sc[36];
    float mx = -1e30f;
    #pragma unroll
    for (int m = 0; m < 36; ++m) {
      const float* kr = qkvb + m * 196 + 64 + hq;
      floatx4 k0f = *(const floatx4*)(kr);
      floatx4 k1f = *(const floatx4*)(kr + 4);
      float s = 0.f;
      #pragma unroll
      for (int e = 0; e < 4; ++e) s += q0[e] * k0f[e];
      #pragma unroll
      for (int e = 0; e < 4; ++e) s += q1[e] * k1f[e];
      s *= 0.35355339059327373f;  // 8^-0.5
      sc[m] = s;
      mx = fmaxf(mx, s);
    }
    float den = 0.f;
    #pragma unroll
    for (int m = 0; m < 36; ++m) { sc[m] = __expf(sc[m] - mx); den += sc[m]; }
    float a[8];
    #pragma unroll
    for (int e = 0; e < 8; ++e) a[e] = 0.f;
    #pragma unroll
    for (int m = 0; m < 36; ++m) {
      const float* vr = qkvb + m * 196 + 128 + hq;
      floatx4 v0f = *(const floatx4*)(vr);
      floatx4 v1f = *(const floatx4*)(vr + 4);
      float p = sc[m];
      #pragma unroll
      for (int e = 0; e < 4; ++e) { a[e] += p * v0f[e]; a[e + 4] += p * v1f[e]; }
    }
    float inv = 1.f / den;
    floatx4 o0, o1;
    #pragma unroll
    for (int e = 0; e < 4; ++e) { o0[e] = a[e] * inv; o1[e] = a[e + 4] * inv; }
    *(floatx4*)(aout + l * 68 + hq) = o0;
    *(floatx4*)(aout + l * 68 + hq + 4) = o1;
  }
  __syncthreads();

  // mat[l][oo] = aout[l][:] . w_out[oo][:] + b_out[oo]   (reuse k0 region)
  float* mat = k0;
  for (int idx = t; idx < 16 * 36; idx += 256) {
    int og = idx / 36, l = idx - og * 36;
    int oo = og << 2;
    const float* ar = aout + l * 68;
    const float* w0 = w_out + oo * 64;
    float a0 = 0.f, a1 = 0.f, a2 = 0.f, a3 = 0.f;
    #pragma unroll
    for (int i = 0; i < 64; i += 4) {
      floatx4 af  = *(const floatx4*)(ar + i);
      floatx4 wf0 = *(const floatx4*)(w0 + i);
      floatx4 wf1 = *(const floatx4*)(w0 + 64 + i);
      floatx4 wf2 = *(const floatx4*)(w0 + 128 + i);
      floatx4 wf3 = *(const floatx4*)(w0 + 192 + i);
      #pragma unroll
      for (int e = 0; e < 4; ++e) {
        a0 += af[e] * wf0[e];
        a1 += af[e] * wf1[e];
        a2 += af[e] * wf2[e];
        a3 += af[e] * wf3[e];
      }
    }
    floatx4 r = { a0 + b_out[oo],     a1 + b_out[oo + 1],
                  a2 + b_out[oo + 2], a3 + b_out[oo + 3] };
    *(floatx4*)(mat + l * 68 + oo) = r;
  }
  __syncthreads();

  // SE gate (qkvb region reused for pooled + h1)
  float* pl = qkvb;        // [4][64]
  float* h1 = qkvb + 256;  // [16]
  {
    int win = t >> 6, I = t & 63;
    float p = 0.f;
    #pragma unroll
    for (int t9 = 0; t9 < 9; ++t9) p += mat[(win * 9 + t9) * 68 + I];
    pl[t] = p * (1.f / 9.f);
  }
  __syncthreads();
  if (t < 16) {
    int win = t >> 2, r = t & 3;
    const float* wr = se_w1 + (win * 4 + r) * 64;
    const float* pr = pl + (win << 6);
    float a = se_b1[win * 4 + r];
    #pragma unroll 8
    for (int i = 0; i < 64; ++i) a += pr[i] * wr[i];
    h1[t] = fmaxf(a, 0.f);
  }
  __syncthreads();
  {
    int win = t >> 6, I = t & 63;
    float a = se_b2[(win << 6) + I];
    #pragma unroll
    for (int r = 0; r < 4; ++r)
      a += h1[win * 4 + r] * se_w2[((win << 6) + I) * 4 + r];
    float s = 1.f / (1.f + __expf(-a));
    #pragma unroll
    for (int t9 = 0; t9 < 9; ++t9) {
      float v = mat[(win * 9 + t9) * 68 + I] * s;
      g_W2[((win * 9 + t9) * 64 + o) * 64 + I] = f2h(v);
    }
  }
}

// ---------------------------------------------------------------------------
// Kernel 2: implicit-GEMM dynamic conv + fused LN + residual
//   block = 256 thr (4 waves), tile = 32w x 8h pixels of one window quadrant
//   x (fp32, channel-major) -> fp16 LDS tile [px][ch] on the fly
//   MFMA 16x16x32 f16: D[px][oc], A = x-tile (LDS), B = g_W2 (L2-resident)
// ---------------------------------------------------------------------------
__global__ __launch_bounds__(256, 3) void conv_kernel(
    const float* __restrict__ x,
    const float* __restrict__ ln_w,
    const float* __restrict__ ln_b,
    float* __restrict__ outp)
{
  __shared__ __align__(16) short xs[24480];  // 340 halo px x pitch 72 = 48.96 KB
  int* xs32 = (int*)xs;
  const int t = threadIdx.x;
  const int wb = blockIdx.x & 7;
  const int hb = (blockIdx.x >> 3) & 31;
  const int b  = blockIdx.x >> 8;
  const int gh0 = hb << 3, gw0 = wb << 5;
  const int hlo = (gh0 >= 128) ? 128 : 0;
  const int wlo = (gw0 >= 128) ? 128 : 0;
  const int win = ((gh0 >= 128) ? 2 : 0) + ((gw0 >= 128) ? 1 : 0);
  const float* xb = x + ((size_t)b << 22);  // b * 64 * 65536

  // ---- stage x tile + halo from channel-major fp32 (zero outside window) ---
  // interior px (cl 1..32): 32 ch-pairs x 10 rows x 4 chunks of 8 px
  #pragma unroll
  for (int it = 0; it < 5; ++it) {
    int idx = t + it * 256;
    int u = idx & 3;
    int r = (idx >> 2) % 10;
    int cp = idx / 40;
    int gh = gh0 + r - 1;
    int gw = gw0 + (u << 3);
    floatx4 a0 = {0.f, 0.f, 0.f, 0.f}, a1 = a0, b0 = a0, b1 = a0;
    if (gh >= hlo && gh < hlo + 128) {   // cols always inside the window here
      const float* p = xb + ((size_t)(2 * cp) << 16) + gh * 256 + gw;
      a0 = *(const floatx4*)p;
      a1 = *(const floatx4*)(p + 4);
      b0 = *(const floatx4*)(p + 65536);
      b1 = *(const floatx4*)(p + 65540);
    }
    int base = (r * 34 + (u << 3) + 1) * 36 + cp;  // int index into xs32
    #pragma unroll
    for (int j = 0; j < 4; ++j) {
      unsigned int pv = (unsigned int)f2h(a0[j]) |
                        ((unsigned int)f2h(b0[j]) << 16);
      xs32[base + j * 36] = (int)pv;
    }
    #pragma unroll
    for (int j = 0; j < 4; ++j) {
      unsigned int pv = (unsigned int)f2h(a1[j]) |
                        ((unsigned int)f2h(b1[j]) << 16);
      xs32[base + (j + 4) * 36] = (int)pv;
    }
  }
  // edge px (cl 0 and 33): guarded scalar loads (handles window borders)
  #pragma unroll
  for (int it = 0; it < 3; ++it) {
    int idx = t + it * 256;
    if (idx < 640) {
      int e = idx & 1;
      int r = (idx >> 1) % 10;
      int cp = idx / 20;
      int gh = gh0 + r - 1;
      int gw = e ? (gw0 + 32) : (gw0 - 1);
      int cl = e ? 33 : 0;
      unsigned int pv = 0;
      if (gh >= hlo && gh < hlo + 128 && gw >= wlo && gw < wlo + 128) {
        const float* p = xb + ((size_t)(2 * cp) << 16) + gh * 256 + gw;
        pv = (unsigned int)f2h(p[0]) | ((unsigned int)f2h(p[65536]) << 16);
      }
      xs32[(r * 34 + cl) * 36 + cp] = (int)pv;
    }
  }
  __syncthreads();

  const int wave = t >> 6, lane = t & 63;
  const int l15 = lane & 15, q = lane >> 4;

  floatx4 acc[4][4];
  #pragma unroll
  for (int mt = 0; mt < 4; ++mt)
    #pragma unroll
    for (int nt = 0; nt < 4; ++nt)
      acc[mt][nt] = (floatx4){0.f, 0.f, 0.f, 0.f};

  // A-fragment base offsets: wave owns pixel rows {2*wave, 2*wave+1}
  int aoff[4];
  #pragma unroll
  for (int mt = 0; mt < 4; ++mt)
    aoff[mt] = ((2 * wave + (mt >> 1)) * 34 + ((mt & 1) << 4) + l15) * 72 + (q << 3);

  // B fragments from g_W2 (L2-resident), double-buffered in registers
  const ushort_t* Wb = g_W2 + win * 36864 + l15 * 64 + (q << 3);
  half8 bcur[4], bnxt[4];
  #pragma unroll
  for (int nt = 0; nt < 4; ++nt)
    bcur[nt] = *(const half8*)(Wb + nt * 1024);

  #pragma unroll
  for (int tap = 0; tap < 9; ++tap) {
    const int ky = tap / 3, kx = tap - ky * 3;
    const int toff = (ky * 34 + kx) * 72;
    #pragma unroll
    for (int kc = 0; kc < 2; ++kc) {
      const int nit = tap * 2 + kc + 1;
      if (nit < 18) {
        const int ntap = nit >> 1, nkc = nit & 1;
        #pragma unroll
        for (int nt = 0; nt < 4; ++nt)
          bnxt[nt] = *(const half8*)(Wb + ntap * 4096 + nkc * 32 + nt * 1024);
      }
      half8 av[4];
      #pragma unroll
      for (int mt = 0; mt < 4; ++mt)
        av[mt] = *(const half8*)(xs + aoff[mt] + toff + kc * 32);
      #pragma unroll
      for (int mt = 0; mt < 4; ++mt)
        #pragma unroll
        for (int nt = 0; nt < 4; ++nt)
          acc[mt][nt] = __builtin_amdgcn_mfma_f32_16x16x32_f16(
              av[mt], bcur[nt], acc[mt][nt], 0, 0, 0);
      #pragma unroll
      for (int nt = 0; nt < 4; ++nt) bcur[nt] = bnxt[nt];
    }
  }

  // ---- fused epilogue: LayerNorm over 64 ch + fp32 residual (re-read x),
  //      direct float4 stores (16 consecutive px * 4 B per 16-lane group) ----
  float lnwv[4], lnbv[4];
  #pragma unroll
  for (int nt = 0; nt < 4; ++nt) {
    int c = (nt << 4) + l15;
    lnwv[nt] = ln_w[c];
    lnbv[nt] = ln_b[c];
  }
  #pragma unroll
  for (int mt = 0; mt < 4; ++mt) {
    const int rr = 2 * wave + (mt >> 1);
    const int colb = (mt & 1) << 4;
    float s1[4], s2[4];
    #pragma unroll
    for (int e = 0; e < 4; ++e) { s1[e] = 0.f; s2[e] = 0.f; }
    #pragma unroll
    for (int nt = 0; nt < 4; ++nt)
      #pragma unroll
      for (int e = 0; e < 4; ++e) {
        float v = acc[mt][nt][e];
        s1[e] += v;
        s2[e] += v * v;
      }
    // quarter-wave butterfly: per-pixel sums over all 64 channels
    #pragma unroll
    for (int m = 1; m < 16; m <<= 1) {
      #pragma unroll
      for (int e = 0; e < 4; ++e) {
        s1[e] += __shfl_xor(s1[e], m, 64);
        s2[e] += __shfl_xor(s2[e], m, 64);
      }
    }
    float mean[4], rstd[4];
    #pragma unroll
    for (int e = 0; e < 4; ++e) {
      mean[e] = s1[e] * 0.015625f;
      float var = s2[e] * 0.015625f - mean[e] * mean[e];
      rstd[e] = rsqrtf(var + 1e-5f);
    }
    #pragma unroll
    for (int nt = 0; nt < 4; ++nt) {
      const int c = (nt << 4) + l15;
      const size_t goff = ((size_t)(b * 64 + c) << 16) +
                          (gh0 + rr) * 256 + gw0 + colb + (q << 2);
      floatx4 xr = *(const floatx4*)(x + goff);   // fp32 residual, L2-warm
      floatx4 v;
      #pragma unroll
      for (int e = 0; e < 4; ++e)
        v[e] = (acc[mt][nt][e] - mean[e]) * rstd[e] * lnwv[nt] + lnbv[nt] + xr[e];
      *(floatx4*)(outp + goff) = v;
    }
  }
}

// ---------------------------------------------------------------------------
extern "C" void kernel_launch(void* const* d_in, const int* in_sizes, int n_in,
                              void* d_out, int out_size, void* d_ws, size_t ws_size,
                              hipStream_t stream) {
  const float* x     = (const float*)d_in[0];
  const float* convw = (const float*)d_in[1];
  const float* wqkv  = (const float*)d_in[2];
  const float* bqkv  = (const float*)d_in[3];
  const float* wout  = (const float*)d_in[4];
  const float* bout  = (const float*)d_in[5];
  const float* sew1  = (const float*)d_in[6];
  const float* seb1  = (const float*)d_in[7];
  const float* sew2  = (const float*)d_in[8];
  const float* seb2  = (const float*)d_in[9];
  const float* lnw   = (const float*)d_in[10];
  const float* lnb   = (const float*)d_in[11];
  float* outp = (float*)d_out;

  hipLaunchKernelGGL(tw_kernel, dim3(64), dim3(256), 0, stream,
                     convw, wqkv, bqkv, wout, bout,
                     sew1, seb1, sew2, seb2);
  hipLaunchKernelGGL(conv_kernel, dim3(2048), dim3(256), 0, stream,
                     x, lnw, lnb, outp);
}